// Round 5
// baseline (974.963 us; speedup 1.0000x reference)
//
#include <hip/hip_runtime.h>
#include <hip/hip_bf16.h>
#include <math.h>

// ---------------------------------------------------------------------------
// QuantumProcessingLayer: out = tanh(concat(f(x), f(x)^2) @ W + b)
//   f(x) = tanh(2pi x) + 0.1*sin(2pi x)*cos(pi x)
// M=16384 (B*S), F=2048, K=4096 (2F), N=2048 (U). fp32 in/out, bf16 MFMA core.
// R7b: resubmit of R7 (container infra failure, no counters). 4-wave /
//     128x128-per-wave geometry. R4-R6 all measured ~252us == exact serial
//     sum of MFMA pipe (1242 cyc/k32/CU) + LDS read pipe (1156 cyc):
//     2-wave-per-SIMD lockstep gave zero pipe overlap. This round cuts LDS
//     fragment replication (4xA+2xB -> 2xA+2xB = 96KB -> 64KB per k32, 770
//     cyc < 1242 MFMA) and gives each SIMD ONE wave: 64 MFMA/phase at 1 per
//     ~19 cyc leaves abundant issue slots for the 16 ds_reads + 8 stage
//     issues; compiler's partial-lgkmcnt pipelining hides read latency
//     in-phase. Counted vmcnt (8 gld/stage): prologue stages slots 0,1,2
//     (24 out); phase h: VM(16) lands slot h ({h+1,h+2} remain); stage(h+3).
//     Tail: h=126 VM(8), h=127 VM(0). Slot (h+3)&3 == (h-1)&3 overwrite is
//     safe: its readers (phase h-1) drained by lgkm0 before this barrier.
// ---------------------------------------------------------------------------

typedef __bf16 b16x8 __attribute__((ext_vector_type(8)));
typedef float f32x4 __attribute__((ext_vector_type(4)));

constexpr int Mdim = 16384;
constexpr int Fdim = 2048;
constexpr int Kdim = 4096;
constexpr int Ndim = 2048;

// tanh(2*pi*x): e = exp(-4*pi*|x|); t = (1-e)/(1+e) via v_rcp
__device__ __forceinline__ float tanh_2pix(float x) {
  float ax = fabsf(x);
  float e = __expf(-12.566370614359172f * ax);
  float t = (1.0f - e) * __builtin_amdgcn_rcpf(1.0f + e);
  return copysignf(t, x);
}

__device__ __forceinline__ float fast_tanh(float x) {
  float ax = fabsf(x);
  float e = __expf(-2.0f * ax);
  float t = (1.0f - e) * __builtin_amdgcn_rcpf(1.0f + e);
  return copysignf(t, x);
}

// ---------------- prologue: feats[m][k] (bf16), k<F: qe, k>=F: qe^2 ---------
struct __align__(16) B8 { __bf16 v[8]; };

__global__ void feats_kernel(const float* __restrict__ x, __bf16* __restrict__ feats) {
  int idx = blockIdx.x * blockDim.x + threadIdx.x;  // one thread per 8 elems
  long i8 = (long)idx << 3;
  float4 xv0 = reinterpret_cast<const float4*>(x)[idx * 2];
  float4 xv1 = reinterpret_cast<const float4*>(x)[idx * 2 + 1];
  float q[8] = {xv0.x, xv0.y, xv0.z, xv0.w, xv1.x, xv1.y, xv1.z, xv1.w};
  B8 qe, en;
#pragma unroll
  for (int j = 0; j < 8; ++j) {
    float xx = q[j];
    // sin(2*pi*x) = v_sin(x revolutions); cos(pi*x) = v_cos(x/2 revolutions)
    float s = __builtin_amdgcn_sinf(xx);
    float c = __builtin_amdgcn_cosf(0.5f * xx);
    float v = tanh_2pix(xx) + 0.1f * s * c;
    qe.v[j] = (__bf16)v;
    en.v[j] = (__bf16)(v * v);
  }
  int m = (int)(i8 >> 11);     // / Fdim
  int f = (int)(i8 & (Fdim - 1));
  size_t base = (size_t)m * Kdim + f;
  *reinterpret_cast<B8*>(feats + base) = qe;
  *reinterpret_cast<B8*>(feats + base + Fdim) = en;
}

// ---------------- W [K][N] fp32  ->  Wt [N][K] bf16 ------------------------
__global__ void wtrans_kernel(const float* __restrict__ W, __bf16* __restrict__ Wt) {
  __shared__ float tile[32][33];
  int bn = blockIdx.x;   // N/32 = 64
  int bk = blockIdx.y;   // K/32 = 128
  int tx = threadIdx.x;  // 0..31
  int ty = threadIdx.y;  // 0..7
#pragma unroll
  for (int i = 0; i < 4; ++i) {
    int kk = bk * 32 + ty + i * 8;
    tile[ty + i * 8][tx] = W[(size_t)kk * Ndim + bn * 32 + tx];
  }
  __syncthreads();
#pragma unroll
  for (int i = 0; i < 4; ++i) {
    int nn = bn * 32 + ty + i * 8;
    Wt[(size_t)nn * Kdim + bk * 32 + tx] = (__bf16)tile[tx][ty + i * 8];
  }
}

// ---------------- GEMM: out = tanh(A @ Wt^T + b) ---------------------------
typedef const __attribute__((address_space(1))) void* gptr1;
typedef __attribute__((address_space(3))) void* lptr3;

__device__ __forceinline__ void gld_lds16(const __bf16* g, __bf16* l) {
  __builtin_amdgcn_global_load_lds((gptr1)g, (lptr3)l, 16, 0, 0);
}

#define BARRIER()    asm volatile("s_barrier" ::: "memory")
#define WAIT_LGKM0() asm volatile("s_waitcnt lgkmcnt(0)" ::: "memory")
#define WAIT_VM(n)   asm volatile("s_waitcnt vmcnt(" #n ")" ::: "memory")

__global__ __launch_bounds__(256, 1) void gemm_tanh_kernel(
    const __bf16* __restrict__ A,    // [M][K] feats
    const __bf16* __restrict__ Bt,   // [N][K] W^T
    const float* __restrict__ bias,  // [N]
    float* __restrict__ out) {       // [M][N]
  // 128 KiB: A slots [4][256 rows][32 k] then B slots [4][256][32]
  __shared__ __align__(16) __bf16 smem[65536];
  __bf16* const sA = smem;           // 4 x 8192 elems
  __bf16* const sB = smem + 32768;   // 4 x 8192 elems

  const int tid = threadIdx.x;
  const int wv = tid >> 6;           // 0..3
  const int lane = tid & 63;

  // T1: XCD-aware bijective swizzle (nwg=512, 512%8==0). Each XCD gets 64
  // consecutive wg = 8 M-tiles x 8 N-tiles -> A-panel L2 reuse.
  const int orig = blockIdx.y * 8 + blockIdx.x;
  const int wg = (orig & 7) * 64 + (orig >> 3);
  const int m0 = (wg >> 3) * 256;
  const int n0 = (wg & 7) * 256;

  const int wm = (wv >> 1) * 128;  // 2x2 wave grid, 128x128 out per wave
  const int wn = (wv & 1) * 128;
  const int lr = lane & 15;
  const int lq = lane >> 4;

  // ---- staging: slot = 256 rows x 32 k = 16 KB = 1024 x 16B chunks.
  // 4 waves x 4 instrs x 64 lanes. Chunk L -> LDS linear; global source
  // chunk pre-swizzled (c = pos ^ ((row>>1)&3)) so the read-side XOR
  // pattern (0 bank conflicts, measured R2-R6) sees its data.
  const __bf16* gA[4];
  const __bf16* gB[4];
  int dstoff[4];
#pragma unroll
  for (int q = 0; q < 4; ++q) {
    int L = wv * 256 + q * 64 + lane;
    int r = L >> 2;
    int c = (L & 3) ^ ((r >> 1) & 3);
    gA[q] = A + (size_t)(m0 + r) * Kdim + c * 8;
    gB[q] = Bt + (size_t)(n0 + r) * Kdim + c * 8;
    dstoff[q] = wv * 2048 + q * 512;  // wave-uniform (HW adds lane*16B)
  }

  auto stage = [&](int h) {   // 8 gld: A half-tile h + B half-tile h
    const int sl = (h & 3) * 8192;
#pragma unroll
    for (int q = 0; q < 4; ++q) gld_lds16(gA[q] + h * 32, sA + sl + dstoff[q]);
#pragma unroll
    for (int q = 0; q < 4; ++q) gld_lds16(gB[q] + h * 32, sB + sl + dstoff[q]);
  };

  // ---- fragment read offsets (XOR-swizzled chunk; row swizzle bits depend
  // only on lr since wm/i*16 are multiples of 16) ---------------------------
  const int chunk = (lq ^ ((lr >> 1) & 3)) * 8;
  const int ard = (wm + lr) * 32 + chunk;
  const int brd = (wn + lr) * 32 + chunk;

  f32x4 acc[8][8];
#pragma unroll
  for (int i = 0; i < 8; ++i)
#pragma unroll
    for (int j = 0; j < 8; ++j) acc[i][j] = (f32x4){0.f, 0.f, 0.f, 0.f};

  b16x8 av[8], bv[8];

  // Bias loaded & drained BEFORE staging (keeps the vmcnt queue exact).
  float bval[8];
#pragma unroll
  for (int j = 0; j < 8; ++j) bval[j] = bias[n0 + wn + j * 16 + lr];
  WAIT_VM(0);

  // ---- prologue: stage slots 0,1,2 (24 gld outstanding) -------------------
  stage(0); stage(1); stage(2);

  // ---- main loop: 128 phases (one k=32 half-tile each) --------------------
  for (int h = 0; h < 128; ++h) {
    if (h < 126) {
      WAIT_VM(16);        // slot h landed ({h+1,h+2} = 16 remain)
    } else if (h == 126) {
      WAIT_VM(8);         // slot 126 landed ({127} = 8 remain)
    } else {
      WAIT_VM(0);         // slot 127 landed
    }
    WAIT_LGKM0();         // phase h-1's frag reads drained (slot reuse safety)
    BARRIER();
    if (h <= 124) stage(h + 3);   // overwrites slot (h-1)&3 -- safe past barrier

    const int sl = (h & 3) * 8192;
#pragma unroll
    for (int i = 0; i < 8; ++i)
      av[i] = *reinterpret_cast<const b16x8*>(sA + sl + ard + i * 512);
#pragma unroll
    for (int i = 0; i < 8; ++i)
      bv[i] = *reinterpret_cast<const b16x8*>(sB + sl + brd + i * 512);

    __builtin_amdgcn_s_setprio(1);
#pragma unroll
    for (int j = 0; j < 8; ++j)
#pragma unroll
      for (int i = 0; i < 8; ++i)
        acc[i][j] = __builtin_amdgcn_mfma_f32_16x16x32_bf16(av[i], bv[j], acc[i][j], 0, 0, 0);
    __builtin_amdgcn_s_setprio(0);
  }

  // ---- epilogue: C/D layout col=lane&15, row=(lane>>4)*4+reg --------------
#pragma unroll
  for (int j = 0; j < 8; ++j) {
    const int gn = n0 + wn + j * 16 + lr;
#pragma unroll
    for (int i = 0; i < 8; ++i) {
      const int gm = m0 + wm + i * 16 + lq * 4;
#pragma unroll
      for (int r = 0; r < 4; ++r) {
        float v = acc[i][j][r] + bval[j];
        out[(size_t)(gm + r) * Ndim + gn] = fast_tanh(v);
      }
    }
  }
}

// ---------------------------------------------------------------------------
extern "C" void kernel_launch(void* const* d_in, const int* in_sizes, int n_in,
                              void* d_out, int out_size, void* d_ws, size_t ws_size,
                              hipStream_t stream) {
  const float* x = (const float*)d_in[0];
  const float* W = (const float*)d_in[1];
  const float* b = (const float*)d_in[2];
  float* out = (float*)d_out;

  // ws layout: Wt bf16 [N*K] (16.8 MB) | feats bf16 [M*K] (134 MB)
  __bf16* Wt = (__bf16*)d_ws;
  __bf16* feats = Wt + (size_t)Ndim * Kdim;

  hipLaunchKernelGGL(feats_kernel, dim3(Mdim * Fdim / 8 / 256), dim3(256), 0,
                     stream, x, feats);
  hipLaunchKernelGGL(wtrans_kernel, dim3(Ndim / 32, Kdim / 32), dim3(32, 8), 0,
                     stream, W, Wt);
  hipLaunchKernelGGL(gemm_tanh_kernel, dim3(Ndim / 256, Mdim / 256), dim3(256),
                     0, stream, feats, Wt, b, out);
}